// Round 2
// baseline (108.886 us; speedup 1.0000x reference)
//
#include <hip/hip_runtime.h>
#include <stdint.h>

#define NB 128        // batch rows
#define NV 128000     // vocab
#define NT 1024       // threads per block
#define NV4 (NV / 4)  // 32000 float4s per row
#define NBINS 16384   // 14-bit sortable-key prefix histogram
#define CCAP 2048     // candidate capacity (typical ~70-100)
#define TOPC 63       // max rank ever sampleable (top_ks <= 63)

// JAX threefry random_bits variant:
// 0 = partitionable, take low word  (o1)   [round 0: FAILED]
// 1 = partitionable, take high word (o0)
// 2 = partitionable, xor both words (o0^o1) [this round]
// 3 = legacy non-partitionable split-iota layout
#define PRNG_VARIANT 2

__device__ __forceinline__ uint32_t rotl32(uint32_t v, uint32_t d) {
  return (v << d) | (v >> (32u - d));
}

// Threefry-2x32, 20 rounds, matching jax._src.prng.threefry2x32.
__device__ __forceinline__ void threefry2x32(uint32_t k0, uint32_t k1,
                                             uint32_t x0, uint32_t x1,
                                             uint32_t& o0, uint32_t& o1) {
  uint32_t ks2 = k0 ^ k1 ^ 0x1BD11BDAu;
  x0 += k0; x1 += k1;
#define TF_ROUND(r) { x0 += x1; x1 = rotl32(x1, (r)); x1 ^= x0; }
  TF_ROUND(13) TF_ROUND(15) TF_ROUND(26) TF_ROUND(6)
  x0 += k1;  x1 += ks2 + 1u;
  TF_ROUND(17) TF_ROUND(29) TF_ROUND(16) TF_ROUND(24)
  x0 += ks2; x1 += k0 + 2u;
  TF_ROUND(13) TF_ROUND(15) TF_ROUND(26) TF_ROUND(6)
  x0 += k0;  x1 += k1 + 3u;
  TF_ROUND(17) TF_ROUND(29) TF_ROUND(16) TF_ROUND(24)
  x0 += k1;  x1 += ks2 + 4u;
  TF_ROUND(13) TF_ROUND(15) TF_ROUND(26) TF_ROUND(6)
  x0 += ks2; x1 += k0 + 5u;
#undef TF_ROUND
  o0 = x0; o1 = x1;
}

// bits for flat element n of gumbel((B,V)) under jax.random.key(42)
__device__ __forceinline__ uint32_t jax_random_bits_u32(uint64_t n) {
#if PRNG_VARIANT == 3
  const uint32_t half = (uint32_t)((uint64_t)NB * NV / 2);
  uint32_t o0, o1;
  uint32_t n32 = (uint32_t)n;
  if (n32 < half) { threefry2x32(0u, 42u, n32, n32 + half, o0, o1); return o0; }
  else            { threefry2x32(0u, 42u, n32 - half, n32, o0, o1); return o1; }
#else
  uint32_t o0, o1;
  threefry2x32(0u, 42u, (uint32_t)(n >> 32), (uint32_t)n, o0, o1);
#if PRNG_VARIANT == 0
  return o1;
#elif PRNG_VARIANT == 1
  return o0;
#else
  return o0 ^ o1;
#endif
#endif
}

// JAX: uniform(key, minval=tiny, maxval=1.) -> gumbel = -log(-log(u))
__device__ __forceinline__ float gumbel_from_bits(uint32_t bits) {
  const float tiny = 1.17549435e-38f;
  float f = __uint_as_float(0x3f800000u | (bits >> 9)) - 1.0f;  // [0,1)
  float u = f * 1.0f + tiny;        // (maxval-minval) rounds to 1.0f in f32
  u = fmaxf(tiny, u);
  return -logf(-logf(u));
}

// Monotone (ascending) uint mapping of float ordering.
__device__ __forceinline__ uint32_t sortkey(float x) {
  uint32_t b = __float_as_uint(x);
  uint32_t mask = (uint32_t)((int32_t)b >> 31) | 0x80000000u;
  return b ^ mask;
}

__global__ __launch_bounds__(NT) void sampler_kernel(
    const float* __restrict__ logits, const float* __restrict__ temps,
    const float* __restrict__ topps, const float* __restrict__ topks,
    float* __restrict__ out) {

  __shared__ union {
    uint32_t hist[NBINS];                // 64 KB  (phase 2)
    unsigned long long cand[CCAP];       // 16 KB  (phases 3-4, reuses hist mem)
  } sh;
  __shared__ uint32_t ssum[NT];          // 4 KB suffix-scan
  __shared__ float redf[NT];             // 4 KB reductions
  __shared__ uint32_t s_cutkey, s_cnt;
  __shared__ int s_tstar;
  __shared__ float sp[TOPC], scum[TOPC], slv[TOPC];
  __shared__ int sidx_[TOPC];

  const int b = blockIdx.x;
  const int t = threadIdx.x;
  const float temp = temps[b];
  const float st = (temp == 0.0f) ? 1.0f : temp;
  const float topp = topps[b];
  const float topk = topks[b];

  const float4* __restrict__ lrow = (const float4*)(logits + (size_t)b * NV);
  float4* __restrict__ srow = (float4*)(out + NB + (size_t)b * NV);

  // zero histogram (visible after phase-1 reduction barriers)
  for (int i = t; i < NBINS; i += NT) sh.hist[i] = 0u;
  if (t == 0) s_tstar = NT - 1;

  // ---- phase 1: scaled = logits / safe_t (write output 1), row max ----
  float lmax = -INFINITY;
  for (int i = t; i < NV4; i += NT) {
    float4 x = lrow[i];
    float4 s;
    s.x = x.x / st; s.y = x.y / st; s.z = x.z / st; s.w = x.w / st;
    srow[i] = s;
    lmax = fmaxf(lmax, fmaxf(fmaxf(s.x, s.y), fmaxf(s.z, s.w)));
  }
  redf[t] = lmax;
  __syncthreads();
  for (int off = NT / 2; off > 0; off >>= 1) {
    if (t < off) redf[t] = fmaxf(redf[t], redf[t + off]);
    __syncthreads();
  }
  const float m = redf[0];
  __syncthreads();

  // ---- phase 2: Z = sum(exp(scaled - m)); histogram of key>>18 ----
  float lsum = 0.0f;
  for (int i = t; i < NV4; i += NT) {
    float4 x = lrow[i];
    float s0 = x.x / st, s1 = x.y / st, s2 = x.z / st, s3 = x.w / st;
    lsum += expf(s0 - m); lsum += expf(s1 - m);
    lsum += expf(s2 - m); lsum += expf(s3 - m);
    atomicAdd(&sh.hist[sortkey(s0) >> 18], 1u);
    atomicAdd(&sh.hist[sortkey(s1) >> 18], 1u);
    atomicAdd(&sh.hist[sortkey(s2) >> 18], 1u);
    atomicAdd(&sh.hist[sortkey(s3) >> 18], 1u);
  }
  redf[t] = lsum;
  __syncthreads();
  for (int off = NT / 2; off > 0; off >>= 1) {
    if (t < off) redf[t] += redf[t + off];
    __syncthreads();
  }
  const float Z = redf[0];
  __syncthreads();

  // ---- find cut bin: smallest bin c with count(key-bin >= c) >= 63 ----
  uint32_t sloc = 0;
  #pragma unroll
  for (int j = 0; j < 16; ++j) sloc += sh.hist[t * 16 + j];
  ssum[t] = sloc;
  __syncthreads();
  for (int off = 1; off < NT; off <<= 1) {   // inclusive suffix sums
    uint32_t v = ssum[t] + ((t + off < NT) ? ssum[t + off] : 0u);
    __syncthreads();
    ssum[t] = v;
    __syncthreads();
  }
  if (ssum[t] >= 63u && (t == NT - 1 || ssum[t + 1] < 63u)) s_tstar = t;
  __syncthreads();
  if (t == 0) {
    int ts = s_tstar;
    uint32_t running = (ts == NT - 1) ? 0u : ssum[ts + 1];
    int cutbin = ts * 16;
    for (int j = 15; j >= 0; --j) {
      running += sh.hist[ts * 16 + j];
      if (running >= 63u) { cutbin = ts * 16 + j; break; }
    }
    s_cutkey = (uint32_t)cutbin << 18;
    s_cnt = 0u;
  }
  __syncthreads();
  const uint32_t cutkey = s_cutkey;

  // ---- phase 3: gather candidates (key >= cutkey) into LDS ----
  for (int i = t; i < NV4; i += NT) {
    float4 x = lrow[i];
    float sv[4];
    sv[0] = x.x / st; sv[1] = x.y / st; sv[2] = x.z / st; sv[3] = x.w / st;
    #pragma unroll
    for (int j = 0; j < 4; ++j) {
      uint32_t key = sortkey(sv[j]);
      if (key >= cutkey) {
        float p = expf(sv[j] - m) / Z;  // exact softmax elementwise div
        uint32_t pos = atomicAdd(&s_cnt, 1u);
        if (pos < CCAP) {
          uint32_t idx = (uint32_t)(i * 4 + j);
          sh.cand[pos] = ((unsigned long long)__float_as_uint(p) << 32)
                       | (unsigned long long)(0xFFFFFFFFu - idx);
        }
      }
    }
  }
  __syncthreads();
  const uint32_t cnt = s_cnt;
  for (int e = t; e < CCAP; e += NT)
    if ((uint32_t)e >= cnt) sh.cand[e] = 0ull;   // pad sorts last
  __syncthreads();

  // ---- phase 4: bitonic sort CCAP u64 keys, descending => (p desc, idx asc)
  for (uint32_t k = 2; k <= CCAP; k <<= 1) {
    for (uint32_t j = k >> 1; j > 0; j >>= 1) {
      for (int e = t; e < CCAP; e += NT) {
        uint32_t ixj = (uint32_t)e ^ j;
        if (ixj > (uint32_t)e) {
          unsigned long long a = sh.cand[e], c = sh.cand[ixj];
          bool desc = (((uint32_t)e & k) == 0u);
          if (desc ? (a < c) : (a > c)) { sh.cand[e] = c; sh.cand[ixj] = a; }
        }
      }
      __syncthreads();
    }
  }

  // ---- phase 5: top-63 tail ----
  if (t < TOPC) {
    unsigned long long kv = sh.cand[t];
    sp[t] = __uint_as_float((uint32_t)(kv >> 32));
    sidx_[t] = (int)(0xFFFFFFFFu - (uint32_t)(kv & 0xFFFFFFFFull));
  }
  __syncthreads();
  if (t == 0) {
    // XLA associative_scan-structured cumsum of sp[0..62]
    float L0[63], L1[31], L2[15], L3[7], L4[3];
    for (int i = 0; i < 63; ++i) L0[i] = sp[i];
    for (int i = 0; i < 31; ++i) L1[i] = L0[2*i] + L0[2*i+1];
    for (int i = 0; i < 15; ++i) L2[i] = L1[2*i] + L1[2*i+1];
    for (int i = 0; i < 7;  ++i) L3[i] = L2[2*i] + L2[2*i+1];
    for (int i = 0; i < 3;  ++i) L4[i] = L3[2*i] + L3[2*i+1];
    float S5 = L4[0] + L4[1];
    float S4[3]; S4[0] = L4[0]; S4[1] = S5; S4[2] = S5 + L4[2];
    float S3[7]; S3[0] = L3[0];
    for (int k = 0; k < 3; ++k) { S3[2*k+1] = S4[k]; if (2*k+2 < 7)  S3[2*k+2] = S4[k] + L3[2*k+2]; }
    float S2[15]; S2[0] = L2[0];
    for (int k = 0; k < 7; ++k) { S2[2*k+1] = S3[k]; if (2*k+2 < 15) S2[2*k+2] = S3[k] + L2[2*k+2]; }
    float S1[31]; S1[0] = L1[0];
    for (int k = 0; k < 15; ++k){ S1[2*k+1] = S2[k]; if (2*k+2 < 31) S1[2*k+2] = S2[k] + L1[2*k+2]; }
    scum[0] = L0[0];
    for (int k = 0; k < 31; ++k){ scum[2*k+1] = S1[k]; if (2*k+2 < 63) scum[2*k+2] = S1[k] + L0[2*k+2]; }
  }
  __syncthreads();
  if (t < TOPC) {
    bool keep = (((float)t < topk) && ((scum[t] - sp[t]) < topp)) || (t == 0);
    uint32_t bits = jax_random_bits_u32((uint64_t)b * NV + (uint64_t)t);
    float g = gumbel_from_bits(bits);
    slv[t] = keep ? (logf(sp[t]) + g) : -INFINITY;
  }
  __syncthreads();
  if (t == 0) {
    float best = slv[0]; int br = 0;
    for (int r = 1; r < TOPC; ++r)
      if (slv[r] > best) { best = slv[r]; br = r; }
    int id = (temp == 0.0f) ? sidx_[0] : sidx_[br];
    out[b] = (float)id;   // ids < 2^24, exact in f32
  }
}

extern "C" void kernel_launch(void* const* d_in, const int* in_sizes, int n_in,
                              void* d_out, int out_size, void* d_ws, size_t ws_size,
                              hipStream_t stream) {
  const float* logits = (const float*)d_in[0];
  const float* temps  = (const float*)d_in[1];
  const float* topps  = (const float*)d_in[2];
  const float* topks  = (const float*)d_in[3];
  float* out = (float*)d_out;
  hipLaunchKernelGGL(sampler_kernel, dim3(NB), dim3(NT), 0, stream,
                     logits, temps, topps, topks, out);
}

// Round 3
// 64.827 us; speedup vs baseline: 1.6796x; 1.6796x over previous
//
#include <hip/hip_runtime.h>
#include <stdint.h>

#define NB 128        // batch rows
#define NV 128000     // vocab
#define TOPC 63       // max rank ever sampleable (top_ks <= 63)

// ---- fast path geometry ----
#define JPB 8                 // chunks per row
#define CH 16000              // floats per chunk (NV/JPB)
#define CH4 4000              // float4s per chunk
#define K1T 256               // K1 threads
#define HB 8192               // histogram bins (sortkey >> 19)
#define CSLOT 256             // candidate slots per chunk
#define CCAP2 2048            // max total candidates per row (JPB*CSLOT)
#define NBLK1 (NB * JPB)      // 1024 K1 blocks

// ws layout (bytes)
#define WS_CAND_OFF 0
#define WS_CAND_BYTES ((size_t)NBLK1 * CSLOT * 8)          // 2 MiB
#define WS_M_OFF (WS_CAND_BYTES)
#define WS_S_OFF (WS_M_OFF + NBLK1 * 4)
#define WS_CNT_OFF (WS_S_OFF + NBLK1 * 4)
#define WS_NEED (WS_CNT_OFF + NBLK1 * 4)

// ---- fallback (round-2 monolithic) geometry ----
#define NT 1024
#define NV4 (NV / 4)
#define NBINS 16384
#define CCAP 2048

__device__ __forceinline__ uint32_t rotl32(uint32_t v, uint32_t d) {
  return (v << d) | (v >> (32u - d));
}

// Threefry-2x32, 20 rounds, matching jax._src.prng.threefry2x32.
__device__ __forceinline__ void threefry2x32(uint32_t k0, uint32_t k1,
                                             uint32_t x0, uint32_t x1,
                                             uint32_t& o0, uint32_t& o1) {
  uint32_t ks2 = k0 ^ k1 ^ 0x1BD11BDAu;
  x0 += k0; x1 += k1;
#define TF_ROUND(r) { x0 += x1; x1 = rotl32(x1, (r)); x1 ^= x0; }
  TF_ROUND(13) TF_ROUND(15) TF_ROUND(26) TF_ROUND(6)
  x0 += k1;  x1 += ks2 + 1u;
  TF_ROUND(17) TF_ROUND(29) TF_ROUND(16) TF_ROUND(24)
  x0 += ks2; x1 += k0 + 2u;
  TF_ROUND(13) TF_ROUND(15) TF_ROUND(26) TF_ROUND(6)
  x0 += k0;  x1 += k1 + 3u;
  TF_ROUND(17) TF_ROUND(29) TF_ROUND(16) TF_ROUND(24)
  x0 += k1;  x1 += ks2 + 4u;
  TF_ROUND(13) TF_ROUND(15) TF_ROUND(26) TF_ROUND(6)
  x0 += ks2; x1 += k0 + 5u;
#undef TF_ROUND
  o0 = x0; o1 = x1;
}

// partitionable random_bits, u32 = xor of the two threefry words (verified round 2)
__device__ __forceinline__ uint32_t jax_random_bits_u32(uint64_t n) {
  uint32_t o0, o1;
  threefry2x32(0u, 42u, (uint32_t)(n >> 32), (uint32_t)n, o0, o1);
  return o0 ^ o1;
}

// JAX: uniform(key, minval=tiny, maxval=1.) -> gumbel = -log(-log(u))
__device__ __forceinline__ float gumbel_from_bits(uint32_t bits) {
  const float tiny = 1.17549435e-38f;
  float f = __uint_as_float(0x3f800000u | (bits >> 9)) - 1.0f;  // [0,1)
  float u = f * 1.0f + tiny;
  u = fmaxf(tiny, u);
  return -logf(-logf(u));
}

// Monotone (ascending) uint mapping of float ordering.
__device__ __forceinline__ uint32_t sortkey(float x) {
  uint32_t b = __float_as_uint(x);
  uint32_t mask = (uint32_t)((int32_t)b >> 31) | 0x80000000u;
  return b ^ mask;
}

// ======================= fast path =======================

// K1: per-chunk fused pass. grid = NBLK1, block = K1T.
__global__ __launch_bounds__(K1T) void k1_scan(
    const float* __restrict__ logits, const float* __restrict__ temps,
    float* __restrict__ out, unsigned long long* __restrict__ cand,
    float* __restrict__ m_arr, float* __restrict__ S_arr,
    uint32_t* __restrict__ cnt_arr) {

  __shared__ uint32_t hist[HB];          // 32 KB
  __shared__ float redm[K1T], reds[K1T];
  __shared__ uint32_t ssum[K1T];
  __shared__ int s_tstar;
  __shared__ uint32_t s_cutkey, s_lcnt;

  const int bid = blockIdx.x;
  const int r = bid >> 3, j = bid & 7;
  const int t = threadIdx.x;
  const float temp = temps[r];
  const float st = (temp == 0.0f) ? 1.0f : temp;

  const float4* __restrict__ lrow4 =
      (const float4*)(logits + (size_t)r * NV + (size_t)j * CH);
  float4* __restrict__ srow4 =
      (float4*)(out + NB + (size_t)r * NV + (size_t)j * CH);

  for (int i = t; i < HB; i += K1T) hist[i] = 0u;
  if (t == 0) { s_tstar = K1T - 1; s_lcnt = 0u; }
  __syncthreads();

  // pass A: scale + write + per-thread online (m, sumexp) + histogram
  float mr = -INFINITY, sr = 0.0f;
  for (int i = t; i < CH4; i += K1T) {
    float4 x = lrow4[i];
    float4 s;
    s.x = x.x / st; s.y = x.y / st; s.z = x.z / st; s.w = x.w / st;
    srow4[i] = s;
    float sv[4] = {s.x, s.y, s.z, s.w};
    #pragma unroll
    for (int q = 0; q < 4; ++q) {
      float s1 = sv[q];
      if (s1 > mr) { sr *= expf(mr - s1); mr = s1; }  // mr=-inf first iter: sr stays 0
      sr += expf(s1 - mr);
      atomicAdd(&hist[sortkey(s1) >> 19], 1u);
    }
  }
  redm[t] = mr; reds[t] = sr;
  __syncthreads();
  for (int off = K1T / 2; off > 0; off >>= 1) {
    if (t < off) {
      float ma = redm[t], mb = redm[t + off];
      float nm = fmaxf(ma, mb);
      reds[t] = reds[t] * expf(ma - nm) + reds[t + off] * expf(mb - nm);
      redm[t] = nm;
    }
    __syncthreads();
  }
  if (t == 0) { m_arr[bid] = redm[0]; S_arr[bid] = reds[0]; }

  // local cut for chunk top-63: suffix scan of 8192 bins with 256 threads
  uint32_t sloc = 0;
  #pragma unroll
  for (int q = 0; q < HB / K1T; ++q) sloc += hist[t * (HB / K1T) + q];
  ssum[t] = sloc;
  __syncthreads();
  for (int off = 1; off < K1T; off <<= 1) {
    uint32_t v = ssum[t] + ((t + off < K1T) ? ssum[t + off] : 0u);
    __syncthreads();
    ssum[t] = v;
    __syncthreads();
  }
  if (ssum[t] >= 63u && (t == K1T - 1 || ssum[t + 1] < 63u)) s_tstar = t;
  __syncthreads();
  if (t == 0) {
    int ts = s_tstar;
    uint32_t running = (ts == K1T - 1) ? 0u : ssum[ts + 1];
    int cutbin = ts * (HB / K1T);
    for (int q = HB / K1T - 1; q >= 0; --q) {
      running += hist[ts * (HB / K1T) + q];
      if (running >= 63u) { cutbin = ts * (HB / K1T) + q; break; }
    }
    s_cutkey = (uint32_t)cutbin << 19;
  }
  __syncthreads();
  const uint32_t cutkey = s_cutkey;

  // pass C: extract candidates (L2-hot re-read of just-written scaled row)
  unsigned long long* __restrict__ mycand = cand + (size_t)bid * CSLOT;
  for (int i = t; i < CH4; i += K1T) {
    float4 s4 = srow4[i];
    float sv[4] = {s4.x, s4.y, s4.z, s4.w};
    #pragma unroll
    for (int q = 0; q < 4; ++q) {
      if (sortkey(sv[q]) >= cutkey) {
        uint32_t pos = atomicAdd(&s_lcnt, 1u);
        if (pos < CSLOT) {
          uint32_t idx = (uint32_t)(j * CH + i * 4 + q);
          mycand[pos] = ((unsigned long long)idx << 32)
                      | (unsigned long long)__float_as_uint(sv[q]);
        }
      }
    }
  }
  __syncthreads();
  if (t == 0) cnt_arr[bid] = (s_lcnt < CSLOT) ? s_lcnt : (uint32_t)CSLOT;
}

// K2: per-row finalize. grid = NB, block = 1024.
__global__ __launch_bounds__(1024) void k2_final(
    const float* __restrict__ temps, const float* __restrict__ topps,
    const float* __restrict__ topks,
    const unsigned long long* __restrict__ cand,
    const float* __restrict__ m_arr, const float* __restrict__ S_arr,
    const uint32_t* __restrict__ cnt_arr, float* __restrict__ out) {

  __shared__ unsigned long long sc[CCAP2];   // 16 KB
  __shared__ float sm8[JPB], ss8[JPB];
  __shared__ uint32_t soff[JPB + 1];
  __shared__ float s_m, s_Z;
  __shared__ int s_P;
  __shared__ float sp[TOPC], scum[TOPC], slv[TOPC];
  __shared__ int sidx_[TOPC];

  const int r = blockIdx.x, t = threadIdx.x;
  const float temp = temps[r];
  const float topp = topps[r];
  const float topk = topks[r];

  if (t < JPB) { sm8[t] = m_arr[r * JPB + t]; ss8[t] = S_arr[r * JPB + t]; }
  __syncthreads();
  if (t == 0) {
    float m = sm8[0];
    for (int q = 1; q < JPB; ++q) m = fmaxf(m, sm8[q]);
    float Z = 0.0f;
    for (int q = 0; q < JPB; ++q) Z += ss8[q] * expf(sm8[q] - m);
    s_m = m; s_Z = Z;
    uint32_t off = 0;
    for (int q = 0; q < JPB; ++q) { soff[q] = off; off += cnt_arr[r * JPB + q]; }
    soff[JPB] = off;                 // total <= JPB*CSLOT = 2048
    int P = 64;
    while (P < (int)off) P <<= 1;
    s_P = P;
  }
  __syncthreads();
  const float m = s_m, Z = s_Z;
  const int total = (int)soff[JPB];
  const int P = s_P;

  // gather candidates -> (p_bits desc, idx asc) packed keys
  for (int e = t; e < P; e += 1024) {
    unsigned long long v = 0ull;
    if (e < total) {
      int q = 0;
      while (e >= (int)soff[q + 1]) ++q;
      unsigned long long c = cand[(size_t)(r * JPB + q) * CSLOT + (e - (int)soff[q])];
      uint32_t idx = (uint32_t)(c >> 32);
      float s = __uint_as_float((uint32_t)c);
      float p = expf(s - m) / Z;     // identical formula to validated round-2 kernel
      v = ((unsigned long long)__float_as_uint(p) << 32)
        | (unsigned long long)(0xFFFFFFFFu - idx);
    }
    sc[e] = v;
  }
  __syncthreads();

  // bitonic sort P keys descending => (p desc, idx asc)
  for (int k = 2; k <= P; k <<= 1) {
    for (int jj = k >> 1; jj > 0; jj >>= 1) {
      for (int e = t; e < P; e += 1024) {
        int ixj = e ^ jj;
        if (ixj > e) {
          unsigned long long a = sc[e], c = sc[ixj];
          bool desc = ((e & k) == 0);
          if (desc ? (a < c) : (a > c)) { sc[e] = c; sc[ixj] = a; }
        }
      }
      __syncthreads();
    }
  }

  // top-63 tail (validated in round 2)
  if (t < TOPC) {
    unsigned long long kv = sc[t];
    sp[t] = __uint_as_float((uint32_t)(kv >> 32));
    sidx_[t] = (int)(0xFFFFFFFFu - (uint32_t)(kv & 0xFFFFFFFFull));
  }
  __syncthreads();
  if (t == 0) {
    float L0[63], L1[31], L2[15], L3[7], L4[3];
    for (int i = 0; i < 63; ++i) L0[i] = sp[i];
    for (int i = 0; i < 31; ++i) L1[i] = L0[2*i] + L0[2*i+1];
    for (int i = 0; i < 15; ++i) L2[i] = L1[2*i] + L1[2*i+1];
    for (int i = 0; i < 7;  ++i) L3[i] = L2[2*i] + L2[2*i+1];
    for (int i = 0; i < 3;  ++i) L4[i] = L3[2*i] + L3[2*i+1];
    float S5 = L4[0] + L4[1];
    float S4[3]; S4[0] = L4[0]; S4[1] = S5; S4[2] = S5 + L4[2];
    float S3[7]; S3[0] = L3[0];
    for (int k = 0; k < 3; ++k) { S3[2*k+1] = S4[k]; if (2*k+2 < 7)  S3[2*k+2] = S4[k] + L3[2*k+2]; }
    float S2[15]; S2[0] = L2[0];
    for (int k = 0; k < 7; ++k) { S2[2*k+1] = S3[k]; if (2*k+2 < 15) S2[2*k+2] = S3[k] + L2[2*k+2]; }
    float S1[31]; S1[0] = L1[0];
    for (int k = 0; k < 15; ++k){ S1[2*k+1] = S2[k]; if (2*k+2 < 31) S1[2*k+2] = S2[k] + L1[2*k+2]; }
    scum[0] = L0[0];
    for (int k = 0; k < 31; ++k){ scum[2*k+1] = S1[k]; if (2*k+2 < 63) scum[2*k+2] = S1[k] + L0[2*k+2]; }
  }
  __syncthreads();
  if (t < TOPC) {
    bool keep = (((float)t < topk) && ((scum[t] - sp[t]) < topp)) || (t == 0);
    uint32_t bits = jax_random_bits_u32((uint64_t)r * NV + (uint64_t)t);
    float g = gumbel_from_bits(bits);
    slv[t] = keep ? (logf(sp[t]) + g) : -INFINITY;
  }
  __syncthreads();
  if (t == 0) {
    float best = slv[0]; int br = 0;
    for (int q = 1; q < TOPC; ++q)
      if (slv[q] > best) { best = slv[q]; br = q; }
    int id = (temp == 0.0f) ? sidx_[0] : sidx_[br];
    out[r] = (float)id;
  }
}

// ======================= fallback: round-2 monolithic kernel =======================

__global__ __launch_bounds__(NT) void sampler_kernel(
    const float* __restrict__ logits, const float* __restrict__ temps,
    const float* __restrict__ topps, const float* __restrict__ topks,
    float* __restrict__ out) {

  __shared__ union {
    uint32_t hist[NBINS];
    unsigned long long cand[CCAP];
  } sh;
  __shared__ uint32_t ssum[NT];
  __shared__ float redf[NT];
  __shared__ uint32_t s_cutkey, s_cnt;
  __shared__ int s_tstar;
  __shared__ float sp[TOPC], scum[TOPC], slv[TOPC];
  __shared__ int sidx_[TOPC];

  const int b = blockIdx.x;
  const int t = threadIdx.x;
  const float temp = temps[b];
  const float st = (temp == 0.0f) ? 1.0f : temp;
  const float topp = topps[b];
  const float topk = topks[b];

  const float4* __restrict__ lrow = (const float4*)(logits + (size_t)b * NV);
  float4* __restrict__ srow = (float4*)(out + NB + (size_t)b * NV);

  for (int i = t; i < NBINS; i += NT) sh.hist[i] = 0u;
  if (t == 0) s_tstar = NT - 1;

  float lmax = -INFINITY;
  for (int i = t; i < NV4; i += NT) {
    float4 x = lrow[i];
    float4 s;
    s.x = x.x / st; s.y = x.y / st; s.z = x.z / st; s.w = x.w / st;
    srow[i] = s;
    lmax = fmaxf(lmax, fmaxf(fmaxf(s.x, s.y), fmaxf(s.z, s.w)));
  }
  redf[t] = lmax;
  __syncthreads();
  for (int off = NT / 2; off > 0; off >>= 1) {
    if (t < off) redf[t] = fmaxf(redf[t], redf[t + off]);
    __syncthreads();
  }
  const float m = redf[0];
  __syncthreads();

  float lsum = 0.0f;
  for (int i = t; i < NV4; i += NT) {
    float4 x = lrow[i];
    float s0 = x.x / st, s1 = x.y / st, s2 = x.z / st, s3 = x.w / st;
    lsum += expf(s0 - m); lsum += expf(s1 - m);
    lsum += expf(s2 - m); lsum += expf(s3 - m);
    atomicAdd(&sh.hist[sortkey(s0) >> 18], 1u);
    atomicAdd(&sh.hist[sortkey(s1) >> 18], 1u);
    atomicAdd(&sh.hist[sortkey(s2) >> 18], 1u);
    atomicAdd(&sh.hist[sortkey(s3) >> 18], 1u);
  }
  redf[t] = lsum;
  __syncthreads();
  for (int off = NT / 2; off > 0; off >>= 1) {
    if (t < off) redf[t] += redf[t + off];
    __syncthreads();
  }
  const float Z = redf[0];
  __syncthreads();

  uint32_t sloc = 0;
  #pragma unroll
  for (int j = 0; j < 16; ++j) sloc += sh.hist[t * 16 + j];
  ssum[t] = sloc;
  __syncthreads();
  for (int off = 1; off < NT; off <<= 1) {
    uint32_t v = ssum[t] + ((t + off < NT) ? ssum[t + off] : 0u);
    __syncthreads();
    ssum[t] = v;
    __syncthreads();
  }
  if (ssum[t] >= 63u && (t == NT - 1 || ssum[t + 1] < 63u)) s_tstar = t;
  __syncthreads();
  if (t == 0) {
    int ts = s_tstar;
    uint32_t running = (ts == NT - 1) ? 0u : ssum[ts + 1];
    int cutbin = ts * 16;
    for (int j = 15; j >= 0; --j) {
      running += sh.hist[ts * 16 + j];
      if (running >= 63u) { cutbin = ts * 16 + j; break; }
    }
    s_cutkey = (uint32_t)cutbin << 18;
    s_cnt = 0u;
  }
  __syncthreads();
  const uint32_t cutkey = s_cutkey;

  for (int i = t; i < NV4; i += NT) {
    float4 x = lrow[i];
    float sv[4];
    sv[0] = x.x / st; sv[1] = x.y / st; sv[2] = x.z / st; sv[3] = x.w / st;
    #pragma unroll
    for (int j = 0; j < 4; ++j) {
      uint32_t key = sortkey(sv[j]);
      if (key >= cutkey) {
        float p = expf(sv[j] - m) / Z;
        uint32_t pos = atomicAdd(&s_cnt, 1u);
        if (pos < CCAP) {
          uint32_t idx = (uint32_t)(i * 4 + j);
          sh.cand[pos] = ((unsigned long long)__float_as_uint(p) << 32)
                       | (unsigned long long)(0xFFFFFFFFu - idx);
        }
      }
    }
  }
  __syncthreads();
  const uint32_t cnt = s_cnt;
  for (int e = t; e < CCAP; e += NT)
    if ((uint32_t)e >= cnt) sh.cand[e] = 0ull;
  __syncthreads();

  for (uint32_t k = 2; k <= CCAP; k <<= 1) {
    for (uint32_t j = k >> 1; j > 0; j >>= 1) {
      for (int e = t; e < CCAP; e += NT) {
        uint32_t ixj = (uint32_t)e ^ j;
        if (ixj > (uint32_t)e) {
          unsigned long long a = sh.cand[e], c = sh.cand[ixj];
          bool desc = (((uint32_t)e & k) == 0u);
          if (desc ? (a < c) : (a > c)) { sh.cand[e] = c; sh.cand[ixj] = a; }
        }
      }
      __syncthreads();
    }
  }

  if (t < TOPC) {
    unsigned long long kv = sh.cand[t];
    sp[t] = __uint_as_float((uint32_t)(kv >> 32));
    sidx_[t] = (int)(0xFFFFFFFFu - (uint32_t)(kv & 0xFFFFFFFFull));
  }
  __syncthreads();
  if (t == 0) {
    float L0[63], L1[31], L2[15], L3[7], L4[3];
    for (int i = 0; i < 63; ++i) L0[i] = sp[i];
    for (int i = 0; i < 31; ++i) L1[i] = L0[2*i] + L0[2*i+1];
    for (int i = 0; i < 15; ++i) L2[i] = L1[2*i] + L1[2*i+1];
    for (int i = 0; i < 7;  ++i) L3[i] = L2[2*i] + L2[2*i+1];
    for (int i = 0; i < 3;  ++i) L4[i] = L3[2*i] + L3[2*i+1];
    float S5 = L4[0] + L4[1];
    float S4[3]; S4[0] = L4[0]; S4[1] = S5; S4[2] = S5 + L4[2];
    float S3[7]; S3[0] = L3[0];
    for (int k = 0; k < 3; ++k) { S3[2*k+1] = S4[k]; if (2*k+2 < 7)  S3[2*k+2] = S4[k] + L3[2*k+2]; }
    float S2[15]; S2[0] = L2[0];
    for (int k = 0; k < 7; ++k) { S2[2*k+1] = S3[k]; if (2*k+2 < 15) S2[2*k+2] = S3[k] + L2[2*k+2]; }
    float S1[31]; S1[0] = L1[0];
    for (int k = 0; k < 15; ++k){ S1[2*k+1] = S2[k]; if (2*k+2 < 31) S1[2*k+2] = S2[k] + L1[2*k+2]; }
    scum[0] = L0[0];
    for (int k = 0; k < 31; ++k){ scum[2*k+1] = S1[k]; if (2*k+2 < 63) scum[2*k+2] = S1[k] + L0[2*k+2]; }
  }
  __syncthreads();
  if (t < TOPC) {
    bool keep = (((float)t < topk) && ((scum[t] - sp[t]) < topp)) || (t == 0);
    uint32_t bits = jax_random_bits_u32((uint64_t)b * NV + (uint64_t)t);
    float g = gumbel_from_bits(bits);
    slv[t] = keep ? (logf(sp[t]) + g) : -INFINITY;
  }
  __syncthreads();
  if (t == 0) {
    float best = slv[0]; int br = 0;
    for (int q = 1; q < TOPC; ++q)
      if (slv[q] > best) { best = slv[q]; br = q; }
    int id = (temp == 0.0f) ? sidx_[0] : sidx_[br];
    out[b] = (float)id;
  }
}

extern "C" void kernel_launch(void* const* d_in, const int* in_sizes, int n_in,
                              void* d_out, int out_size, void* d_ws, size_t ws_size,
                              hipStream_t stream) {
  const float* logits = (const float*)d_in[0];
  const float* temps  = (const float*)d_in[1];
  const float* topps  = (const float*)d_in[2];
  const float* topks  = (const float*)d_in[3];
  float* out = (float*)d_out;

  if (ws_size >= WS_NEED) {
    unsigned long long* cand = (unsigned long long*)((char*)d_ws + WS_CAND_OFF);
    float* m_arr = (float*)((char*)d_ws + WS_M_OFF);
    float* S_arr = (float*)((char*)d_ws + WS_S_OFF);
    uint32_t* cnt_arr = (uint32_t*)((char*)d_ws + WS_CNT_OFF);
    hipLaunchKernelGGL(k1_scan, dim3(NBLK1), dim3(K1T), 0, stream,
                       logits, temps, out, cand, m_arr, S_arr, cnt_arr);
    hipLaunchKernelGGL(k2_final, dim3(NB), dim3(1024), 0, stream,
                       temps, topps, topks, cand, m_arr, S_arr, cnt_arr, out);
  } else {
    hipLaunchKernelGGL(sampler_kernel, dim3(NB), dim3(NT), 0, stream,
                       logits, temps, topps, topks, out);
  }
}